// Round 6
// baseline (799.571 us; speedup 1.0000x reference)
//
#include <hip/hip_runtime.h>
#include <hip/hip_bf16.h>
#include <float.h>

#define IN_DIM 128
#define EDGE_DIM 32
#define HID 64
#define NEG_HUGE (-3.402823466e+38f)

// CAS-loop float atomic max (no NaNs in this pipeline; init sentinel NEG_HUGE)
__device__ __forceinline__ void atomicMaxF(float* addr, float val) {
    unsigned* ua = (unsigned*)addr;
    unsigned cur = *ua;
    while (__uint_as_float(cur) < val) {
        unsigned old = atomicCAS(ua, cur, __float_as_uint(val));
        if (old == cur) break;
        cur = old;
    }
}

// ---------------- K0: init workspace + detect edge_index word stride ----------------
// (int64 edge_index would have zero odd words; int32 has nonzero ones)
__global__ void k_init(float* mmax, float* ssum, float* fwd, float* bwd,
                       float* stats, int* sflag, const int* ei32, int N, int NH) {
    int i = blockIdx.x * blockDim.x + threadIdx.x;
    int stride = gridDim.x * blockDim.x;
    if (i == 0) {
        int odd_or = ei32[1] | ei32[3] | ei32[5] | ei32[7] | ei32[9] | ei32[11];
        sflag[0] = (odd_or == 0) ? 2 : 1;
    }
    for (int j = i; j < NH; j += stride) { fwd[j] = NEG_HUGE; bwd[j] = NEG_HUGE; }
    for (int j = i; j < N; j += stride) { mmax[j] = NEG_HUGE; ssum[j] = 0.0f; }
    for (int j = i; j < 256; j += stride) stats[j] = 0.0f;
}

// ---------------- K1: u = W_src@a, v = W_dest@a, w = W_edge@a ----------------
__global__ void k_uvw(const float* __restrict__ Wsrc, const float* __restrict__ Wdst,
                      const float* __restrict__ Wedge, const float* __restrict__ avec,
                      float* u, float* v, float* w) {
    int t = threadIdx.x;  // 256 threads
    if (t < IN_DIM) {
        float acc = 0.f;
        for (int j = 0; j < HID; j++) acc += Wsrc[t * HID + j] * avec[j];
        u[t] = acc;
    } else {
        int i = t - IN_DIM;
        float acc = 0.f;
        for (int j = 0; j < HID; j++) acc += Wdst[i * HID + j] * avec[j];
        v[i] = acc;
    }
    if (t < EDGE_DIM) {
        float acc = 0.f;
        for (int j = 0; j < HID; j++) acc += Wedge[t * HID + j] * avec[j];
        w[t] = acc;
    }
}

// ---------------- K2: p[n] = x[n].u, q[n] = x[n].v (one wave per node) ----------------
__global__ void k_pq(const float* __restrict__ x, const float* __restrict__ u,
                     const float* __restrict__ v, float* p, float* q, int N) {
    int wave = (blockIdx.x * blockDim.x + threadIdx.x) >> 6;
    int lane = threadIdx.x & 63;
    if (wave >= N) return;
    const float* xr = x + (size_t)wave * IN_DIM;
    float a0 = xr[lane], a1 = xr[lane + 64];
    float pp = a0 * u[lane] + a1 * u[lane + 64];
    float qq = a0 * v[lane] + a1 * v[lane + 64];
    for (int m = 32; m >= 1; m >>= 1) { pp += __shfl_xor(pp, m); qq += __shfl_xor(qq, m); }
    if (lane == 0) { p[wave] = pp; q[wave] = qq; }
}

// ---------------- K3: score[e] = leaky_relu(p[row]+q[col]+edge_attr[e].w) ----------------
__global__ void k_escore(const float* __restrict__ ea, const int* __restrict__ ei,
                         const int* __restrict__ sflag,
                         const float* __restrict__ w, const float* __restrict__ p,
                         const float* __restrict__ q, float* scores, int E) {
    int gid = blockIdx.x * blockDim.x + threadIdx.x;
    int e = gid >> 5;   // 32 lanes per edge
    int j = gid & 31;
    if (e >= E) return;
    float val = ea[(size_t)e * EDGE_DIM + j] * w[j];
    for (int m = 16; m >= 1; m >>= 1) val += __shfl_xor(val, m);
    if (j == 0) {
        int s = sflag[0];
        int r = ei[(size_t)s * e];
        int c = ei[(size_t)s * (E + e)];
        float sc = val + p[r] + q[c];
        scores[e] = (sc > 0.f) ? sc : 0.2f * sc;
    }
}

// ---------------- K4: segment max of scores over col ----------------
__global__ void k_segmax(const float* __restrict__ scores, const int* __restrict__ ei,
                         const int* __restrict__ sflag, float* mmax, int E) {
    int e = blockIdx.x * blockDim.x + threadIdx.x;
    if (e >= E) return;
    int s = sflag[0];
    int c = ei[(size_t)s * (E + e)];
    atomicMaxF(&mmax[c], scores[e]);
}

// ---------------- K5: ev = exp(score-m[col]); ssum[col]+=ev; scores<-ev ----------------
__global__ void k_expsum(float* scores, const int* __restrict__ ei,
                         const int* __restrict__ sflag,
                         const float* __restrict__ mmax, float* ssum, int E) {
    int e = blockIdx.x * blockDim.x + threadIdx.x;
    if (e >= E) return;
    int s = sflag[0];
    int c = ei[(size_t)s * (E + e)];
    float ev = expf(scores[e] - mmax[c]);
    scores[e] = ev;
    atomicAdd(&ssum[c], ev);
}

// ---------------- K6: msg*attn; scatter-max into fwd(col), bwd(row) ----------------
__global__ void k_scatter(const float* __restrict__ exps, const float* __restrict__ msg,
                          const int* __restrict__ ei, const int* __restrict__ sflag,
                          const float* __restrict__ ssum,
                          float* fwd, float* bwd, int E) {
    int gid = blockIdx.x * blockDim.x + threadIdx.x;
    int e = gid >> 6;
    int h = gid & 63;
    if (e >= E) return;
    int s = sflag[0];
    int r = ei[(size_t)s * e];
    int c = ei[(size_t)s * (E + e)];
    float attn = exps[e] / ssum[c];
    float v = msg[(size_t)e * HID + h] * attn;
    atomicMaxF(&fwd[(size_t)c * HID + h], v);
    atomicMaxF(&bwd[(size_t)r * HID + h], v);
}

// ---------------- K7: pre1[n,h] = b1[h] + sum_k cat(fwd,bwd)[n,k]*W1[k,h] ----------------
__global__ void k_mlp1(const float* __restrict__ fwd, const float* __restrict__ bwd,
                       const float* __restrict__ W1, const float* __restrict__ b1,
                       float* pre1, int N) {
    int gid = blockIdx.x * blockDim.x + threadIdx.x;
    int n = gid >> 6, h = gid & 63;
    if (n >= N) return;
    const float* fr = fwd + (size_t)n * HID;
    const float* br = bwd + (size_t)n * HID;
    float acc = b1[h];
    for (int k = 0; k < HID; k++) {
        float fv = fr[k]; fv = (fv == NEG_HUGE) ? 0.f : fv;   // scatter_max0 semantics
        acc += fv * W1[k * HID + h];
    }
    for (int k = 0; k < HID; k++) {
        float bv = br[k]; bv = (bv == NEG_HUGE) ? 0.f : bv;
        acc += bv * W1[(HID + k) * HID + h];
    }
    pre1[(size_t)n * HID + h] = acc;
}

// ---------------- K8: per-feature sum / sum-sq over rows ----------------
__global__ __launch_bounds__(256) void k_stats(const float* __restrict__ pre,
                                               float* gsum, float* gss, int N) {
    __shared__ float lsum[HID], lss[HID];
    int t = threadIdx.x;
    if (t < HID) { lsum[t] = 0.f; lss[t] = 0.f; }
    __syncthreads();
    int h = t & 63, lr = t >> 6;
    float s = 0.f, ss = 0.f;
    for (int n = blockIdx.x * 4 + lr; n < N; n += gridDim.x * 4) {
        float vv = pre[(size_t)n * HID + h];
        s += vv; ss += vv * vv;
    }
    atomicAdd(&lsum[h], s);
    atomicAdd(&lss[h], ss);
    __syncthreads();
    if (t < HID) { atomicAdd(&gsum[t], lsum[t]); atomicAdd(&gss[t], lss[t]); }
}

// ---------------- K9: finalize BN -> scale/shift ----------------
__global__ void k_bnfin(const float* __restrict__ gsum, const float* __restrict__ gss,
                        const float* __restrict__ g, const float* __restrict__ b,
                        float* scale, float* shift, int N) {
    int t = threadIdx.x;
    if (t >= HID) return;
    float invN = 1.0f / (float)N;
    float mu = gsum[t] * invN;
    float var = gss[t] * invN - mu * mu;
    float rs = rsqrtf(var + 1e-5f);
    float sc = rs * g[t];
    scale[t] = sc;
    shift[t] = b[t] - mu * sc;
}

// ---------------- K10: pre2[n,h] = b2[h] + sum_k relu(bn1(pre1))[n,k]*W2[k,h] ----------------
__global__ void k_mlp2(const float* __restrict__ pre1, const float* __restrict__ scale1,
                       const float* __restrict__ shift1,
                       const float* __restrict__ W2, const float* __restrict__ b2v,
                       float* pre2, int N) {
    int gid = blockIdx.x * blockDim.x + threadIdx.x;
    int n = gid >> 6, h = gid & 63;
    if (n >= N) return;
    const float* pr = pre1 + (size_t)n * HID;
    float acc = b2v[h];
    for (int k = 0; k < HID; k++) {
        float z = pr[k] * scale1[k] + shift1[k];
        z = (z > 0.f) ? z : 0.f;
        acc += z * W2[k * HID + h];
    }
    pre2[(size_t)n * HID + h] = acc;
}

// ---------------- K11: h2 = relu(bn2(pre2)); gate = sigmoid(h2@amw+amb); FLOAT32 out ----------------
__global__ void k_out(const float* __restrict__ pre2, const float* __restrict__ scale2,
                      const float* __restrict__ shift2, const float* __restrict__ amw,
                      const float* __restrict__ amb, float* out, int N) {
    int gid = blockIdx.x * blockDim.x + threadIdx.x;
    int n = gid >> 6, h = gid & 63;
    if (n >= N) return;
    float z = pre2[(size_t)n * HID + h] * scale2[h] + shift2[h];
    float h2 = (z > 0.f) ? z : 0.f;
    out[(size_t)n * HID + h] = h2;
    float part = h2 * amw[h];
    for (int m = 32; m >= 1; m >>= 1) part += __shfl_xor(part, m);
    if (h == 0) {
        float gate = 1.0f / (1.0f + expf(-(part + amb[0])));
        out[(size_t)N * HID + n] = gate;
    }
}

extern "C" void kernel_launch(void* const* d_in, const int* in_sizes, int n_in,
                              void* d_out, int out_size, void* d_ws, size_t ws_size,
                              hipStream_t stream) {
    const float* x     = (const float*)d_in[0];
    const int*   ei    = (const int*)d_in[1];
    const float* ea    = (const float*)d_in[2];
    const float* msg   = (const float*)d_in[3];
    const float* Wsrc  = (const float*)d_in[4];
    const float* Wdst  = (const float*)d_in[5];
    const float* Wedge = (const float*)d_in[6];
    const float* avec  = (const float*)d_in[7];
    const float* W1    = (const float*)d_in[8];
    const float* b1    = (const float*)d_in[9];
    const float* g1    = (const float*)d_in[10];
    const float* bb1   = (const float*)d_in[11];
    const float* W2    = (const float*)d_in[12];
    const float* b2    = (const float*)d_in[13];
    const float* g2    = (const float*)d_in[14];
    const float* bb2   = (const float*)d_in[15];
    const float* amw   = (const float*)d_in[16];
    const float* amb   = (const float*)d_in[17];
    float* out = (float*)d_out;   // reference output dtype is float32

    const int N = in_sizes[0] / IN_DIM;   // 50000
    const int E = in_sizes[1] / 2;        // 800000
    const int NH = N * HID;

    // Workspace layout (floats), total = 1024 + 4N + E + 3NH ~= 42.4 MB
    float* ws = (float*)d_ws;
    float* u      = ws;              // 128
    float* v      = u + 128;         // 128
    float* w      = v + 128;         // 32
    float* gsum1  = w + 32;          // stats block: 256 floats zeroed
    float* gss1   = gsum1 + 64;
    float* gsum2  = gss1 + 64;
    float* gss2   = gsum2 + 64;
    float* scale1 = gss2 + 64;
    float* shift1 = scale1 + 64;
    float* scale2 = shift1 + 64;
    float* shift2 = scale2 + 64;
    int*   sflag  = (int*)(shift2 + 64);
    float* p      = ws + 1024;       // N
    float* q      = p + N;           // N
    float* scores = q + N;           // E
    float* mmax   = scores + E;      // N
    float* ssum   = mmax + N;        // N
    float* fwd    = ssum + N;        // NH
    float* bwd    = fwd + (size_t)NH;    // NH
    float* pre1   = bwd + (size_t)NH;    // NH (separate, no alias)
    float* pre2   = fwd;                 // alias dead fwd region (mlp2 reads only pre1)

    hipLaunchKernelGGL(k_init, dim3(2048), dim3(256), 0, stream,
                       mmax, ssum, fwd, bwd, gsum1, sflag, ei, N, NH);
    hipLaunchKernelGGL(k_uvw, dim3(1), dim3(256), 0, stream,
                       Wsrc, Wdst, Wedge, avec, u, v, w);
    hipLaunchKernelGGL(k_pq, dim3((N * 64 + 255) / 256), dim3(256), 0, stream,
                       x, u, v, p, q, N);
    hipLaunchKernelGGL(k_escore, dim3((E * 32 + 255) / 256), dim3(256), 0, stream,
                       ea, ei, sflag, w, p, q, scores, E);
    hipLaunchKernelGGL(k_segmax, dim3((E + 255) / 256), dim3(256), 0, stream,
                       scores, ei, sflag, mmax, E);
    hipLaunchKernelGGL(k_expsum, dim3((E + 255) / 256), dim3(256), 0, stream,
                       scores, ei, sflag, mmax, ssum, E);
    hipLaunchKernelGGL(k_scatter, dim3((int)(((size_t)E * 64 + 255) / 256)), dim3(256), 0, stream,
                       scores, msg, ei, sflag, ssum, fwd, bwd, E);
    hipLaunchKernelGGL(k_mlp1, dim3((N * 64 + 255) / 256), dim3(256), 0, stream,
                       fwd, bwd, W1, b1, pre1, N);
    hipLaunchKernelGGL(k_stats, dim3(1024), dim3(256), 0, stream,
                       pre1, gsum1, gss1, N);
    hipLaunchKernelGGL(k_bnfin, dim3(1), dim3(64), 0, stream,
                       gsum1, gss1, g1, bb1, scale1, shift1, N);
    hipLaunchKernelGGL(k_mlp2, dim3((N * 64 + 255) / 256), dim3(256), 0, stream,
                       pre1, scale1, shift1, W2, b2, pre2, N);
    hipLaunchKernelGGL(k_stats, dim3(1024), dim3(256), 0, stream,
                       pre2, gsum2, gss2, N);
    hipLaunchKernelGGL(k_bnfin, dim3(1), dim3(64), 0, stream,
                       gsum2, gss2, g2, bb2, scale2, shift2, N);
    hipLaunchKernelGGL(k_out, dim3((N * 64 + 255) / 256), dim3(256), 0, stream,
                       pre2, scale2, shift2, amw, amb, out, N);
}

// Round 7
// 672.654 us; speedup vs baseline: 1.1887x; 1.1887x over previous
//
#include <hip/hip_runtime.h>
#include <hip/hip_bf16.h>
#include <float.h>

#define IN_DIM 128
#define EDGE_DIM 32
#define HID 64
#define ENC_NEG_INF 0x007FFFFFu   // encf(-inf)

// Monotone float->uint encoding: unsigned compare == float compare.
// Enables native fire-and-forget atomicMax(unsigned) instead of a CAS loop.
__device__ __forceinline__ unsigned encf(float f) {
    unsigned u = __float_as_uint(f);
    return (u & 0x80000000u) ? ~u : (u | 0x80000000u);
}
__device__ __forceinline__ float decf(unsigned u) {
    return (u & 0x80000000u) ? __uint_as_float(u ^ 0x80000000u) : __uint_as_float(~u);
}
__device__ __forceinline__ float dec0(unsigned u) {  // empty segment (-inf) -> 0
    return (u == ENC_NEG_INF) ? 0.0f : decf(u);
}

// ---------------- K0: init workspace + detect edge_index word stride ----------------
__global__ void k_init(unsigned* mmax, float* ssum, unsigned* fwd, unsigned* bwd,
                       float* stats, int* sflag, const int* ei32, int N, int NH) {
    int i = blockIdx.x * blockDim.x + threadIdx.x;
    int stride = gridDim.x * blockDim.x;
    if (i == 0) {
        int odd_or = ei32[1] | ei32[3] | ei32[5] | ei32[7] | ei32[9] | ei32[11];
        sflag[0] = (odd_or == 0) ? 2 : 1;
    }
    for (int j = i; j < NH; j += stride) { fwd[j] = ENC_NEG_INF; bwd[j] = ENC_NEG_INF; }
    for (int j = i; j < N; j += stride) { mmax[j] = ENC_NEG_INF; ssum[j] = 0.0f; }
    for (int j = i; j < 256; j += stride) stats[j] = 0.0f;
}

// ---------------- K1: u = W_src@a, v = W_dest@a, w = W_edge@a ----------------
__global__ void k_uvw(const float* __restrict__ Wsrc, const float* __restrict__ Wdst,
                      const float* __restrict__ Wedge, const float* __restrict__ avec,
                      float* u, float* v, float* w) {
    int t = threadIdx.x;  // 256 threads
    if (t < IN_DIM) {
        float acc = 0.f;
        for (int j = 0; j < HID; j++) acc += Wsrc[t * HID + j] * avec[j];
        u[t] = acc;
    } else {
        int i = t - IN_DIM;
        float acc = 0.f;
        for (int j = 0; j < HID; j++) acc += Wdst[i * HID + j] * avec[j];
        v[i] = acc;
    }
    if (t < EDGE_DIM) {
        float acc = 0.f;
        for (int j = 0; j < HID; j++) acc += Wedge[t * HID + j] * avec[j];
        w[t] = acc;
    }
}

// ---------------- K2: p[n] = x[n].u, q[n] = x[n].v (one wave per node) ----------------
__global__ void k_pq(const float* __restrict__ x, const float* __restrict__ u,
                     const float* __restrict__ v, float* p, float* q, int N) {
    int wave = (blockIdx.x * blockDim.x + threadIdx.x) >> 6;
    int lane = threadIdx.x & 63;
    if (wave >= N) return;
    const float* xr = x + (size_t)wave * IN_DIM;
    float a0 = xr[lane], a1 = xr[lane + 64];
    float pp = a0 * u[lane] + a1 * u[lane + 64];
    float qq = a0 * v[lane] + a1 * v[lane + 64];
    for (int m = 32; m >= 1; m >>= 1) { pp += __shfl_xor(pp, m); qq += __shfl_xor(qq, m); }
    if (lane == 0) { p[wave] = pp; q[wave] = qq; }
}

// ---------------- K3: score[e] = leaky_relu(p[row]+q[col]+edge_attr[e].w) ----------------
__global__ void k_escore(const float* __restrict__ ea, const int* __restrict__ ei,
                         const int* __restrict__ sflag,
                         const float* __restrict__ w, const float* __restrict__ p,
                         const float* __restrict__ q, float* scores, int E) {
    int gid = blockIdx.x * blockDim.x + threadIdx.x;
    int e = gid >> 5;   // 32 lanes per edge
    int j = gid & 31;
    if (e >= E) return;
    float val = ea[(size_t)e * EDGE_DIM + j] * w[j];
    for (int m = 16; m >= 1; m >>= 1) val += __shfl_xor(val, m);
    if (j == 0) {
        int s = sflag[0];
        int r = ei[(size_t)s * e];
        int c = ei[(size_t)s * (E + e)];
        float sc = val + p[r] + q[c];
        scores[e] = (sc > 0.f) ? sc : 0.2f * sc;
    }
}

// ---------------- K4: segment max of scores over col (native uint atomic) ----------------
__global__ void k_segmax(const float* __restrict__ scores, const int* __restrict__ ei,
                         const int* __restrict__ sflag, unsigned* mmax, int E) {
    int e = blockIdx.x * blockDim.x + threadIdx.x;
    if (e >= E) return;
    int s = sflag[0];
    int c = ei[(size_t)s * (E + e)];
    atomicMax(&mmax[c], encf(scores[e]));
}

// ---------------- K5: ev = exp(score-m[col]); ssum[col]+=ev; scores<-ev ----------------
__global__ void k_expsum(float* scores, const int* __restrict__ ei,
                         const int* __restrict__ sflag,
                         const unsigned* __restrict__ mmax, float* ssum, int E) {
    int e = blockIdx.x * blockDim.x + threadIdx.x;
    if (e >= E) return;
    int s = sflag[0];
    int c = ei[(size_t)s * (E + e)];
    float ev = expf(scores[e] - decf(mmax[c]));
    scores[e] = ev;
    atomicAdd(&ssum[c], ev);
}

// ---------------- K6: msg*attn; scatter-max into fwd(col), bwd(row) ----------------
// Fire-and-forget native atomicMax(unsigned) on encoded floats: no CAS round-trip.
__global__ void k_scatter(const float* __restrict__ exps, const float* __restrict__ msg,
                          const int* __restrict__ ei, const int* __restrict__ sflag,
                          const float* __restrict__ ssum,
                          unsigned* fwd, unsigned* bwd, int E) {
    int gid = blockIdx.x * blockDim.x + threadIdx.x;
    int e = gid >> 6;
    int h = gid & 63;
    if (e >= E) return;
    int s = sflag[0];
    int r = ei[(size_t)s * e];
    int c = ei[(size_t)s * (E + e)];
    float attn = exps[e] / ssum[c];
    float v = msg[(size_t)e * HID + h] * attn;
    unsigned ev = encf(v);
    atomicMax(&fwd[(size_t)c * HID + h], ev);
    atomicMax(&bwd[(size_t)r * HID + h], ev);
}

// ---------------- K7: pre1[n,h] = b1[h] + sum_k cat(fwd,bwd)[n,k]*W1[k,h] ----------------
__global__ void k_mlp1(const unsigned* __restrict__ fwd, const unsigned* __restrict__ bwd,
                       const float* __restrict__ W1, const float* __restrict__ b1,
                       float* pre1, int N) {
    int gid = blockIdx.x * blockDim.x + threadIdx.x;
    int n = gid >> 6, h = gid & 63;
    if (n >= N) return;
    const unsigned* fr = fwd + (size_t)n * HID;
    const unsigned* br = bwd + (size_t)n * HID;
    float acc = b1[h];
    for (int k = 0; k < HID; k++) acc += dec0(fr[k]) * W1[k * HID + h];
    for (int k = 0; k < HID; k++) acc += dec0(br[k]) * W1[(HID + k) * HID + h];
    pre1[(size_t)n * HID + h] = acc;
}

// ---------------- K8: per-feature sum / sum-sq over rows ----------------
__global__ __launch_bounds__(256) void k_stats(const float* __restrict__ pre,
                                               float* gsum, float* gss, int N) {
    __shared__ float lsum[HID], lss[HID];
    int t = threadIdx.x;
    if (t < HID) { lsum[t] = 0.f; lss[t] = 0.f; }
    __syncthreads();
    int h = t & 63, lr = t >> 6;
    float s = 0.f, ss = 0.f;
    for (int n = blockIdx.x * 4 + lr; n < N; n += gridDim.x * 4) {
        float vv = pre[(size_t)n * HID + h];
        s += vv; ss += vv * vv;
    }
    atomicAdd(&lsum[h], s);
    atomicAdd(&lss[h], ss);
    __syncthreads();
    if (t < HID) { atomicAdd(&gsum[t], lsum[t]); atomicAdd(&gss[t], lss[t]); }
}

// ---------------- K9: finalize BN -> scale/shift ----------------
__global__ void k_bnfin(const float* __restrict__ gsum, const float* __restrict__ gss,
                        const float* __restrict__ g, const float* __restrict__ b,
                        float* scale, float* shift, int N) {
    int t = threadIdx.x;
    if (t >= HID) return;
    float invN = 1.0f / (float)N;
    float mu = gsum[t] * invN;
    float var = gss[t] * invN - mu * mu;
    float rs = rsqrtf(var + 1e-5f);
    float sc = rs * g[t];
    scale[t] = sc;
    shift[t] = b[t] - mu * sc;
}

// ---------------- K10: pre2[n,h] = b2[h] + sum_k relu(bn1(pre1))[n,k]*W2[k,h] ----------------
__global__ void k_mlp2(const float* __restrict__ pre1, const float* __restrict__ scale1,
                       const float* __restrict__ shift1,
                       const float* __restrict__ W2, const float* __restrict__ b2v,
                       float* pre2, int N) {
    int gid = blockIdx.x * blockDim.x + threadIdx.x;
    int n = gid >> 6, h = gid & 63;
    if (n >= N) return;
    const float* pr = pre1 + (size_t)n * HID;
    float acc = b2v[h];
    for (int k = 0; k < HID; k++) {
        float z = pr[k] * scale1[k] + shift1[k];
        z = (z > 0.f) ? z : 0.f;
        acc += z * W2[k * HID + h];
    }
    pre2[(size_t)n * HID + h] = acc;
}

// ---------------- K11: h2 = relu(bn2(pre2)); gate = sigmoid(h2@amw+amb); f32 out ----------------
__global__ void k_out(const float* __restrict__ pre2, const float* __restrict__ scale2,
                      const float* __restrict__ shift2, const float* __restrict__ amw,
                      const float* __restrict__ amb, float* out, int N) {
    int gid = blockIdx.x * blockDim.x + threadIdx.x;
    int n = gid >> 6, h = gid & 63;
    if (n >= N) return;
    float z = pre2[(size_t)n * HID + h] * scale2[h] + shift2[h];
    float h2 = (z > 0.f) ? z : 0.f;
    out[(size_t)n * HID + h] = h2;
    float part = h2 * amw[h];
    for (int m = 32; m >= 1; m >>= 1) part += __shfl_xor(part, m);
    if (h == 0) {
        float gate = 1.0f / (1.0f + expf(-(part + amb[0])));
        out[(size_t)N * HID + n] = gate;
    }
}

extern "C" void kernel_launch(void* const* d_in, const int* in_sizes, int n_in,
                              void* d_out, int out_size, void* d_ws, size_t ws_size,
                              hipStream_t stream) {
    const float* x     = (const float*)d_in[0];
    const int*   ei    = (const int*)d_in[1];
    const float* ea    = (const float*)d_in[2];
    const float* msg   = (const float*)d_in[3];
    const float* Wsrc  = (const float*)d_in[4];
    const float* Wdst  = (const float*)d_in[5];
    const float* Wedge = (const float*)d_in[6];
    const float* avec  = (const float*)d_in[7];
    const float* W1    = (const float*)d_in[8];
    const float* b1    = (const float*)d_in[9];
    const float* g1    = (const float*)d_in[10];
    const float* bb1   = (const float*)d_in[11];
    const float* W2    = (const float*)d_in[12];
    const float* b2    = (const float*)d_in[13];
    const float* g2    = (const float*)d_in[14];
    const float* bb2   = (const float*)d_in[15];
    const float* amw   = (const float*)d_in[16];
    const float* amb   = (const float*)d_in[17];
    float* out = (float*)d_out;   // reference output dtype is float32

    const int N = in_sizes[0] / IN_DIM;   // 50000
    const int E = in_sizes[1] / 2;        // 800000
    const int NH = N * HID;

    // Workspace layout (floats), total = 1024 + 4N + E + 3NH ~= 42.4 MB
    float* ws = (float*)d_ws;
    float* u      = ws;              // 128
    float* v      = u + 128;         // 128
    float* w      = v + 128;         // 32
    float* gsum1  = w + 32;          // stats block: 256 floats zeroed
    float* gss1   = gsum1 + 64;
    float* gsum2  = gss1 + 64;
    float* gss2   = gsum2 + 64;
    float* scale1 = gss2 + 64;
    float* shift1 = scale1 + 64;
    float* scale2 = shift1 + 64;
    float* shift2 = scale2 + 64;
    int*   sflag  = (int*)(shift2 + 64);
    float* p      = ws + 1024;       // N
    float* q      = p + N;           // N
    float* scores = q + N;           // E
    unsigned* mmax = (unsigned*)(scores + E);   // N
    float* ssum   = scores + E + N;             // N
    unsigned* fwd = (unsigned*)(ssum + N);      // NH
    unsigned* bwd = fwd + (size_t)NH;           // NH
    float* pre1   = (float*)(bwd + (size_t)NH); // NH (separate, no alias)
    float* pre2   = (float*)fwd;                // alias dead fwd region (mlp2 reads only pre1)

    hipLaunchKernelGGL(k_init, dim3(2048), dim3(256), 0, stream,
                       mmax, ssum, fwd, bwd, gsum1, sflag, ei, N, NH);
    hipLaunchKernelGGL(k_uvw, dim3(1), dim3(256), 0, stream,
                       Wsrc, Wdst, Wedge, avec, u, v, w);
    hipLaunchKernelGGL(k_pq, dim3((N * 64 + 255) / 256), dim3(256), 0, stream,
                       x, u, v, p, q, N);
    hipLaunchKernelGGL(k_escore, dim3((E * 32 + 255) / 256), dim3(256), 0, stream,
                       ea, ei, sflag, w, p, q, scores, E);
    hipLaunchKernelGGL(k_segmax, dim3((E + 255) / 256), dim3(256), 0, stream,
                       scores, ei, sflag, mmax, E);
    hipLaunchKernelGGL(k_expsum, dim3((E + 255) / 256), dim3(256), 0, stream,
                       scores, ei, sflag, mmax, ssum, E);
    hipLaunchKernelGGL(k_scatter, dim3((int)(((size_t)E * 64 + 255) / 256)), dim3(256), 0, stream,
                       scores, msg, ei, sflag, ssum, fwd, bwd, E);
    hipLaunchKernelGGL(k_mlp1, dim3((N * 64 + 255) / 256), dim3(256), 0, stream,
                       fwd, bwd, W1, b1, pre1, N);
    hipLaunchKernelGGL(k_stats, dim3(1024), dim3(256), 0, stream,
                       pre1, gsum1, gss1, N);
    hipLaunchKernelGGL(k_bnfin, dim3(1), dim3(64), 0, stream,
                       gsum1, gss1, g1, bb1, scale1, shift1, N);
    hipLaunchKernelGGL(k_mlp2, dim3((N * 64 + 255) / 256), dim3(256), 0, stream,
                       pre1, scale1, shift1, W2, b2, pre2, N);
    hipLaunchKernelGGL(k_stats, dim3(1024), dim3(256), 0, stream,
                       pre2, gsum2, gss2, N);
    hipLaunchKernelGGL(k_bnfin, dim3(1), dim3(64), 0, stream,
                       gsum2, gss2, g2, bb2, scale2, shift2, N);
    hipLaunchKernelGGL(k_out, dim3((N * 64 + 255) / 256), dim3(256), 0, stream,
                       pre2, scale2, shift2, amw, amb, out, N);
}